// Round 9
// baseline (228.944 us; speedup 1.0000x reference)
//
#include <hip/hip_runtime.h>

#define NC 16384
#define WIN 32
#define DI 16
#define EI 524288

typedef unsigned short u16;
typedef unsigned char u8;
typedef unsigned int u32;
typedef __attribute__((ext_vector_type(8))) short bfrag8;
typedef __attribute__((ext_vector_type(4))) float facc4;

__device__ __forceinline__ float bf2f(u16 u) { return __uint_as_float(((u32)u) << 16); }
__device__ __forceinline__ u16 f2bf(float f) {
    u32 u = __float_as_uint(f);
    u += 0x7FFFu + ((u >> 16) & 1u);
    return (u16)(u >> 16);
}
__device__ __forceinline__ float frcp(float x) { return __builtin_amdgcn_rcpf(x); }
__device__ __forceinline__ float lrelu(float x) { return x >= 0.0f ? x : 0.2f * x; }
__device__ __forceinline__ float loadf(const void* p, size_t i, bool f32) {
    return f32 ? ((const float*)p)[i] : bf2f(((const u16*)p)[i]);
}
__device__ __forceinline__ bool is_f32(const void* gamma) {
    return ((const u32*)gamma)[0] == 0x3F800000u;
}

// ---- ws layout (float offsets) ----
#define O_SCALE 0
#define O_SHIFT 512
#define O_WIH   1024
#define O_WHH   4096
#define O_BIH   16384
#define O_BHH   16576
#define O_G1W   16768
#define O_G1AS  20864
#define O_G1AD  20928
#define O_G1B   20992
#define O_G2W   21056
#define O_G2AS  25152
#define O_G2AD  25216
#define O_G2B   25280
#define O_FB    25344
#define O_LW    25408
#define O_LB    25664
#define O_FW16  25668   /* 12288 u16 */
#define O_BNACC 31812   /* 1024 */
#define O_SEQ   40960   /* 16384*64 f32 */
#define O_H1    1089536 /* 16384*64 bf16 */
#define O_INTRA 1613824 /* 16384*64 bf16 */
#define O_SPOOL 2138112 /* 256*64 f32 partial maxes */
#define O_AS    2158592 /* 16384 f32 */
#define O_AD    2174976 /* 16384 f32 */
#define O_M     2191360 /* 16384*256 u8 */

// ---------------- K0: convert weights + zero bnacc ----------------
__global__ __launch_bounds__(256) void k_convert(const void* __restrict__ gamma,
                                                 const void* __restrict__ wih,
                                                 const void* __restrict__ whh,
                                                 const void* __restrict__ bih,
                                                 const void* __restrict__ bhh,
                                                 const void* __restrict__ g1w,
                                                 const void* __restrict__ g1as,
                                                 const void* __restrict__ g1ad,
                                                 const void* __restrict__ g1b,
                                                 const void* __restrict__ g2w,
                                                 const void* __restrict__ g2as,
                                                 const void* __restrict__ g2ad,
                                                 const void* __restrict__ g2b,
                                                 const void* __restrict__ fw,
                                                 const void* __restrict__ fb,
                                                 const void* __restrict__ lw,
                                                 const void* __restrict__ lb,
                                                 float* __restrict__ ws) {
    int gt = blockIdx.x * 256 + threadIdx.x;
    const int GS = 64 * 256;
    bool f32 = is_f32(gamma);
    u16* fw16 = (u16*)(ws + O_FW16);
    for (int i = gt; i < 3072; i += GS) ws[O_WIH + i] = loadf(wih, i, f32);
    for (int i = gt; i < 12288; i += GS) {
        ws[O_WHH + i] = loadf(whh, i, f32);
        fw16[i] = f32 ? f2bf(((const float*)fw)[i]) : ((const u16*)fw)[i];
    }
    for (int i = gt; i < 192; i += GS) {
        ws[O_BIH + i] = loadf(bih, i, f32);
        ws[O_BHH + i] = loadf(bhh, i, f32);
    }
    for (int i = gt; i < 4096; i += GS) {
        ws[O_G1W + i] = loadf(g1w, i, f32);
        ws[O_G2W + i] = loadf(g2w, i, f32);
    }
    if (gt < 64) {
        ws[O_G1AS + gt] = loadf(g1as, gt, f32);
        ws[O_G1AD + gt] = loadf(g1ad, gt, f32);
        ws[O_G1B + gt] = loadf(g1b, gt, f32);
        ws[O_G2AS + gt] = loadf(g2as, gt, f32);
        ws[O_G2AD + gt] = loadf(g2ad, gt, f32);
        ws[O_G2B + gt] = loadf(g2b, gt, f32);
        ws[O_FB + gt] = loadf(fb, gt, f32);
    }
    if (gt < 256) ws[O_LW + gt] = loadf(lw, gt, f32);
    if (gt < 4) ws[O_LB + gt] = loadf(lb, gt, f32);
    for (int i = gt; i < 1024; i += GS) ws[O_BNACC + i] = 0.f;
}

// ---------------- K1a: BN partial sums (128 blocks) ----------------
__global__ __launch_bounds__(256) void k_bnpart(const void* __restrict__ daily,
                                                const void* __restrict__ gamma,
                                                float* __restrict__ bnacc) {
    __shared__ float rS[256 * 17];
    __shared__ float rQ[256 * 17];
    int w = blockIdx.x >> 2, ch = blockIdx.x & 3;
    int tid = threadIdx.x;
    bool f32 = is_f32(gamma);
    float s[16], q[16];
#pragma unroll
    for (int i = 0; i < 16; i++) { s[i] = 0.f; q[i] = 0.f; }
    for (int it = 0; it < 16; it++) {
        int c = ch * 4096 + it * 256 + tid;
        size_t base = ((size_t)w * NC + c) * DI;
        float v[16];
        if (f32) {
            const float4* p = (const float4*)((const float*)daily + base);
            float4 a = p[0], b = p[1], cc = p[2], d = p[3];
            v[0] = a.x; v[1] = a.y; v[2] = a.z; v[3] = a.w;
            v[4] = b.x; v[5] = b.y; v[6] = b.z; v[7] = b.w;
            v[8] = cc.x; v[9] = cc.y; v[10] = cc.z; v[11] = cc.w;
            v[12] = d.x; v[13] = d.y; v[14] = d.z; v[15] = d.w;
        } else {
            const uint4* p = (const uint4*)((const u16*)daily + base);
            uint4 a = p[0], b = p[1];
            u32 us[8] = {a.x, a.y, a.z, a.w, b.x, b.y, b.z, b.w};
#pragma unroll
            for (int i = 0; i < 8; i++) {
                v[2 * i] = __uint_as_float(us[i] << 16);
                v[2 * i + 1] = __uint_as_float(us[i] & 0xFFFF0000u);
            }
        }
#pragma unroll
        for (int i = 0; i < 16; i++) { s[i] += v[i]; q[i] += v[i] * v[i]; }
    }
#pragma unroll
    for (int i = 0; i < 16; i++) { rS[tid * 17 + i] = s[i]; rQ[tid * 17 + i] = q[i]; }
    __syncthreads();
    int f = tid & 15, g = tid >> 4;
    float ss = 0.f, qq = 0.f;
    for (int t = g * 16; t < g * 16 + 16; t++) { ss += rS[t * 17 + f]; qq += rQ[t * 17 + f]; }
    atomicAdd(&bnacc[w * 16 + f], ss);
    atomicAdd(&bnacc[512 + w * 16 + f], qq);
}

// ---------------- K1b: edge multiplicity histogram (byte-packed) ----------------
__global__ __launch_bounds__(256) void k_edge(const int* __restrict__ edges, u32* __restrict__ M32) {
    int g = blockIdx.x * 256 + threadIdx.x;
    int4 s4 = ((const int4*)edges)[g];
    int4 d4 = ((const int4*)(edges + EI))[g];
    int ss[4] = {s4.x, s4.y, s4.z, s4.w};
    int dd[4] = {d4.x, d4.y, d4.z, d4.w};
#pragma unroll
    for (int i = 0; i < 4; i++) {
        int sl = ss[i] & 255;
        atomicAdd(&M32[dd[i] * 64 + (sl >> 2)], 1u << ((sl & 3) * 8));
    }
}

// ---------------- K2: GRU — 16 comp/block, 4-way hidden split, all-x LDS staging ----------------
// Time loop touches ONLY LDS (no global loads => no vmcnt drain at the per-step barrier).
__global__ __launch_bounds__(256, 4) void k_gru(const void* __restrict__ daily,
                                                const void* __restrict__ gamma,
                                                const void* __restrict__ beta,
                                                const void* __restrict__ h0_g,
                                                const float* __restrict__ ws,
                                                float* __restrict__ seq_out,
                                                u16* __restrict__ h1_out,
                                                float* __restrict__ asg,
                                                float* __restrict__ adg) {
    __shared__ __attribute__((aligned(16))) u16 sHd[2][16 * 72];  // h, A-layout [m][k]
    __shared__ __attribute__((aligned(16))) u16 sXall[512 * 24];  // [(t*16+m)][k<16], stride 24
    __shared__ float sSc[512], sSh[512];
    __shared__ float sRed[2][4][16];
    int tid = threadIdx.x;
    int w = tid >> 6, lane = tid & 63;
    int li = lane & 15, q = lane >> 4;
    int col = w * 16 + li;
    int n0 = blockIdx.x * 16;
    bool f32 = is_f32(gamma);

    // fused bnfin
    for (int f = tid; f < 512; f += 256) {
        float mu = ws[O_BNACC + f] * (1.0f / NC);
        float var = ws[O_BNACC + 512 + f] * (1.0f / NC) - mu * mu;
        float sc = loadf(gamma, f, f32) * rsqrtf(var + 1e-5f);
        sSc[f] = sc;
        sSh[f] = loadf(beta, f, f32) - mu * sc;
    }
    __syncthreads();
    // stage ALL x (32 steps x 16 companies), normalized bf16
    for (int R = tid; R < 512; R += 256) {
        int t = R >> 4, m = R & 15;
        size_t base = ((size_t)t * NC + n0 + m) * DI;
        float xv[16];
        if (f32) {
            const float4* p = (const float4*)((const float*)daily + base);
            float4 a = p[0], b = p[1], c = p[2], d = p[3];
            xv[0] = a.x; xv[1] = a.y; xv[2] = a.z; xv[3] = a.w;
            xv[4] = b.x; xv[5] = b.y; xv[6] = b.z; xv[7] = b.w;
            xv[8] = c.x; xv[9] = c.y; xv[10] = c.z; xv[11] = c.w;
            xv[12] = d.x; xv[13] = d.y; xv[14] = d.z; xv[15] = d.w;
        } else {
            const uint4* p = (const uint4*)((const u16*)daily + base);
            uint4 a = p[0], b = p[1];
            u32 us[8] = {a.x, a.y, a.z, a.w, b.x, b.y, b.z, b.w};
#pragma unroll
            for (int i = 0; i < 8; i++) {
                xv[2 * i] = __uint_as_float(us[i] << 16);
                xv[2 * i + 1] = __uint_as_float(us[i] & 0xFFFF0000u);
            }
        }
        u16 px[16];
#pragma unroll
        for (int i = 0; i < 16; i++) px[i] = f2bf(xv[i] * sSc[t * 16 + i] + sSh[t * 16 + i]);
        *(uint4*)&sXall[R * 24] = *(const uint4*)&px[0];
        *(uint4*)&sXall[R * 24 + 8] = *(const uint4*)&px[8];
    }

    // B-fragments, prescaled: r/z by -1, n by -2 (this wave's 16 cols)
    bfrag8 bh[3][2], bx[3];
#pragma unroll
    for (int g = 0; g < 3; g++) {
        float sc = (g < 2) ? -1.0f : -2.0f;
#pragma unroll
        for (int kc = 0; kc < 2; kc++)
#pragma unroll
            for (int j = 0; j < 8; j++) {
                int k = kc * 32 + q * 8 + j;
                bh[g][kc][j] = (short)f2bf(sc * ws[O_WHH + k * 192 + g * 64 + col]);
            }
#pragma unroll
        for (int j = 0; j < 8; j++) {
            int k = q * 8 + j;
            bx[g][j] = (k < 16) ? (short)f2bf(sc * ws[O_WIH + k * 192 + g * 64 + col]) : (short)0;
        }
    }
    float bR = -1.0f * (ws[O_BIH + col] + ws[O_BHH + col]);
    float bZ = -1.0f * (ws[O_BIH + 64 + col] + ws[O_BHH + 64 + col]);
    float bNX = -2.0f * ws[O_BIH + 128 + col];
    float bNH = -2.0f * ws[O_BHH + 128 + col];

    // h0
    float hC[4];
#pragma unroll
    for (int r = 0; r < 4; r++)
        hC[r] = loadf(h0_g, (size_t)(n0 + q * 4 + r) * 64 + col, f32);
    if (tid < 128) {
        int hr = tid >> 3, hc = (tid & 7) * 8;
        u16 hrow[8];
#pragma unroll
        for (int i = 0; i < 8; i++)
            hrow[i] = f2bf(loadf(h0_g, (size_t)(n0 + hr) * 64 + hc + i, f32));
        *(uint4*)&sHd[0][hr * 72 + hc] = *(const uint4*)&hrow[0];
    }
    __syncthreads();

    bool xl = (q < 2);
    for (int t = 0; t < WIN; t++) {
        int p = t & 1;
        bfrag8 ax = (bfrag8){0, 0, 0, 0, 0, 0, 0, 0};
        if (xl) ax = *(const bfrag8*)&sXall[(t * 16 + li) * 24 + q * 8];
        bfrag8 ah0 = *(const bfrag8*)&sHd[p][li * 72 + q * 8];
        bfrag8 ah1 = *(const bfrag8*)&sHd[p][li * 72 + 32 + q * 8];
        // 9 MFMAs
        facc4 aR = __builtin_amdgcn_mfma_f32_16x16x32_bf16(ah0, bh[0][0], (facc4){bR, bR, bR, bR}, 0, 0, 0);
        facc4 aZ = __builtin_amdgcn_mfma_f32_16x16x32_bf16(ah0, bh[1][0], (facc4){bZ, bZ, bZ, bZ}, 0, 0, 0);
        facc4 aNH = __builtin_amdgcn_mfma_f32_16x16x32_bf16(ah0, bh[2][0], (facc4){bNH, bNH, bNH, bNH}, 0, 0, 0);
        facc4 aNX = __builtin_amdgcn_mfma_f32_16x16x32_bf16(ax, bx[2], (facc4){bNX, bNX, bNX, bNX}, 0, 0, 0);
        aR = __builtin_amdgcn_mfma_f32_16x16x32_bf16(ah1, bh[0][1], aR, 0, 0, 0);
        aZ = __builtin_amdgcn_mfma_f32_16x16x32_bf16(ah1, bh[1][1], aZ, 0, 0, 0);
        aNH = __builtin_amdgcn_mfma_f32_16x16x32_bf16(ah1, bh[2][1], aNH, 0, 0, 0);
        aR = __builtin_amdgcn_mfma_f32_16x16x32_bf16(ax, bx[0], aR, 0, 0, 0);
        aZ = __builtin_amdgcn_mfma_f32_16x16x32_bf16(ax, bx[1], aZ, 0, 0, 0);
        // gates (pre-negated / pre-doubled)
#pragma unroll
        for (int r = 0; r < 4; r++) {
            float gr = frcp(1.0f + __expf(aR[r]));
            float gz = frcp(1.0f + __expf(aZ[r]));
            float narg = aNX[r] + gr * aNH[r];
            float gn = 2.0f * frcp(1.0f + __expf(narg)) - 1.0f;
            hC[r] = gn + gz * (hC[r] - gn);
        }
#pragma unroll
        for (int r = 0; r < 4; r++)
            sHd[p ^ 1][(q * 4 + r) * 72 + col] = f2bf(hC[r]);
        __syncthreads();
    }

    // epilogue: seq_out
#pragma unroll
    for (int r = 0; r < 4; r++)
        seq_out[(size_t)(n0 + q * 4 + r) * 64 + col] = hC[r];

    // h1 = h @ gat1_W (final h in sHd[0]) + as/ad
    const facc4 zf = {0.f, 0.f, 0.f, 0.f};
    bfrag8 a0 = *(const bfrag8*)&sHd[0][li * 72 + q * 8];
    bfrag8 a1 = *(const bfrag8*)&sHd[0][li * 72 + 32 + q * 8];
    bfrag8 bg0, bg1;
#pragma unroll
    for (int j = 0; j < 8; j++) {
        bg0[j] = (short)f2bf(ws[O_G1W + (q * 8 + j) * 64 + col]);
        bg1[j] = (short)f2bf(ws[O_G1W + (32 + q * 8 + j) * 64 + col]);
    }
    facc4 acc = __builtin_amdgcn_mfma_f32_16x16x32_bf16(a0, bg0, zf, 0, 0, 0);
    acc = __builtin_amdgcn_mfma_f32_16x16x32_bf16(a1, bg1, acc, 0, 0, 0);
    float a1s_j = ws[O_G1AS + col], a1d_j = ws[O_G1AD + col];
    float pAs[4], pAd[4];
#pragma unroll
    for (int r = 0; r < 4; r++) {
        h1_out[(size_t)(n0 + q * 4 + r) * 64 + col] = f2bf(acc[r]);
        pAs[r] = acc[r] * a1s_j;
        pAd[r] = acc[r] * a1d_j;
    }
#pragma unroll
    for (int o = 1; o < 16; o <<= 1) {
#pragma unroll
        for (int r = 0; r < 4; r++) {
            pAs[r] += __shfl_xor(pAs[r], o);
            pAd[r] += __shfl_xor(pAd[r], o);
        }
    }
    if (li == 0) {
#pragma unroll
        for (int r = 0; r < 4; r++) {
            sRed[0][w][q * 4 + r] = pAs[r];
            sRed[1][w][q * 4 + r] = pAd[r];
        }
    }
    __syncthreads();
    if (tid < 16) {
        asg[n0 + tid] = sRed[0][0][tid] + sRed[0][1][tid] + sRed[0][2][tid] + sRed[0][3][tid];
        adg[n0 + tid] = sRed[1][0][tid] + sRed[1][1][tid] + sRed[1][2][tid] + sRed[1][3][tid];
    }
}

// ---------------- K3: GAT1 — cooperative P build + MFMA aggregation ----------------
__global__ __launch_bounds__(256) void k_gat1agg(const u16* __restrict__ h1g,
                                                 const float* __restrict__ ws,
                                                 const u8* __restrict__ M8,
                                                 const float* __restrict__ asg,
                                                 const float* __restrict__ adg,
                                                 u16* __restrict__ intra,
                                                 float* __restrict__ spool4) {
    __shared__ __attribute__((aligned(16))) u16 hT[64 * 264];
    __shared__ __attribute__((aligned(16))) u16 sP[64 * 136];
    __shared__ float sAs[256], sAd[64], sB[64], sRS[64];
    __shared__ float sRSp[4][64];
    __shared__ float wmax[4];
    int tid = threadIdx.x;
    int sector = blockIdx.x >> 2;
    int dstbase = sector * 256 + (blockIdx.x & 3) * 64;
    int sbase = sector * 256;
    {
        const u16* row = h1g + (size_t)(sbase + tid) * 64;
#pragma unroll
        for (int c = 0; c < 16; c++) {
            uint2 v = ((const uint2*)row)[c];
            hT[(c * 4 + 0) * 264 + tid] = (u16)(v.x & 0xffff);
            hT[(c * 4 + 1) * 264 + tid] = (u16)(v.x >> 16);
            hT[(c * 4 + 2) * 264 + tid] = (u16)(v.y & 0xffff);
            hT[(c * 4 + 3) * 264 + tid] = (u16)(v.y >> 16);
        }
    }
    sAs[tid] = asg[sbase + tid];
    if (tid < 64) { sAd[tid] = adg[dstbase + tid]; sB[tid] = ws[O_G1B + tid]; }
    __syncthreads();
    int lane = tid & 63, w = tid >> 6;
    int li = lane & 15, q = lane >> 4;
    {
        float a = sAs[tid];
#pragma unroll
        for (int o = 1; o < 64; o <<= 1) a = fmaxf(a, __shfl_xor(a, o));
        if (lane == 0) wmax[w] = a;
    }
    __syncthreads();
    float maxA = fmaxf(fmaxf(wmax[0], wmax[1]), fmaxf(wmax[2], wmax[3]));

    int prow = tid >> 2, pcg = tid & 3;
    float adr_p = sAd[prow];
    float mrow_p = lrelu(maxA + adr_p);
    float lsum = 0.f;

    facc4 acc[4];
#pragma unroll
    for (int mt = 0; mt < 4; mt++) acc[mt] = (facc4){0.f, 0.f, 0.f, 0.f};

#pragma unroll
    for (int half = 0; half < 2; half++) {
        const u8* mp = M8 + (size_t)(dstbase + prow) * 256 + half * 128 + pcg * 32;
        uint4 mva = *(const uint4*)mp;
        uint4 mvb = *(const uint4*)(mp + 16);
        u32 wsrc[8] = {mva.x, mva.y, mva.z, mva.w, mvb.x, mvb.y, mvb.z, mvb.w};
#pragma unroll
        for (int i2 = 0; i2 < 16; i2++) {
            int i0 = 2 * i2;
            u32 mb0 = (wsrc[i0 >> 2] >> ((i0 & 3) * 8)) & 255u;
            u32 mb1 = (wsrc[i0 >> 2] >> (((i0 + 1) & 3) * 8)) & 255u;
            int c = half * 128 + pcg * 32 + i0;
            float e0 = lrelu(sAs[c] + adr_p);
            float e1 = lrelu(sAs[c + 1] + adr_p);
            float v0 = (float)mb0 * __expf(e0 - mrow_p);
            float v1 = (float)mb1 * __expf(e1 - mrow_p);
            u16 b0 = f2bf(v0), b1 = f2bf(v1);
            *(u32*)&sP[prow * 136 + pcg * 32 + i0] = (u32)b0 | ((u32)b1 << 16);
            lsum += bf2f(b0) + bf2f(b1);
        }
        __syncthreads();
#pragma unroll
        for (int kc = 0; kc < 4; kc++) {
            bfrag8 bfh = *(const bfrag8*)&hT[(w * 16 + li) * 264 + half * 128 + kc * 32 + q * 8];
#pragma unroll
            for (int mt = 0; mt < 4; mt++) {
                bfrag8 af = *(const bfrag8*)&sP[(mt * 16 + li) * 136 + kc * 32 + q * 8];
                acc[mt] = __builtin_amdgcn_mfma_f32_16x16x32_bf16(af, bfh, acc[mt], 0, 0, 0);
            }
        }
        __syncthreads();
    }
    sRSp[pcg][prow] = lsum;
    __syncthreads();
    if (tid < 64) sRS[tid] = sRSp[0][tid] + sRSp[1][tid] + sRSp[2][tid] + sRSp[3][tid];
    __syncthreads();

    float vmax = -1e30f;
    int colL = w * 16 + li;
#pragma unroll
    for (int mt = 0; mt < 4; mt++) {
#pragma unroll
        for (int r = 0; r < 4; r++) {
            int row = mt * 16 + q * 4 + r;
            int d = dstbase + row;
            int selfI = (blockIdx.x & 3) * 64 + row;
            float adr = sAd[row];
            float es = lrelu(sAs[selfI] + adr);
            float mrow = lrelu(maxA + adr);
            float exS = __expf(es - mrow);
            float denom = sRS[row] + exS;
            float inv = frcp(denom + 1e-16f);
            float selfh = bf2f(hT[colL * 264 + selfI]);
            float val = (acc[mt][r] + exS * selfh) * inv + sB[colL];
            intra[(size_t)d * 64 + colL] = f2bf(val);
            vmax = fmaxf(vmax, val);
        }
    }
    vmax = fmaxf(vmax, __shfl_xor(vmax, 16));
    vmax = fmaxf(vmax, __shfl_xor(vmax, 32));
    if (q == 0) spool4[(size_t)blockIdx.x * 64 + colL] = vmax;
}

// ---------------- K4: fusion (GAT2 prologue + MFMA fusion GEMM + logits) ----------------
__global__ __launch_bounds__(256) void k_fusion(const float* __restrict__ seq,
                                                const float* __restrict__ spool4,
                                                const u16* __restrict__ intra,
                                                const float* __restrict__ ws,
                                                const void* __restrict__ gamma,
                                                void* __restrict__ out) {
    __shared__ __attribute__((aligned(16))) union {
        struct { float sPt[4096]; float sW2[4096]; float sH2[4096]; } p0;
        struct { u16 sV[64 * 200]; float sFus[64 * 68]; } p1;
    } U;
    __shared__ float sSemb[64], sAs2[64], sAd2[64];
    __shared__ float sFB[64], sLW[256], sLB[4];
    __shared__ float red2[512];
    int tid = threadIdx.x, n0 = blockIdx.x * 64;
    int sid = blockIdx.x >> 2;
    bool f32 = is_f32(gamma);

    for (int i = tid; i < 4096; i += 256) {
        int n = i >> 6, k = i & 63;
        float m = fmaxf(fmaxf(spool4[(n * 4 + 0) * 64 + k], spool4[(n * 4 + 1) * 64 + k]),
                        fmaxf(spool4[(n * 4 + 2) * 64 + k], spool4[(n * 4 + 3) * 64 + k]));
        U.p0.sPt[k * 64 + n] = m;
        U.p0.sW2[i] = ws[O_G2W + i];
    }
    __syncthreads();
    {
        int n = tid >> 2, jg = tid & 3, j0 = jg * 16;
        float acc0[16];
#pragma unroll
        for (int i = 0; i < 16; i++) acc0[i] = 0.f;
        for (int k = 0; k < 64; k++) {
            float a = U.p0.sPt[k * 64 + n];
#pragma unroll
            for (int i = 0; i < 16; i += 4) {
                float4 w4 = *(const float4*)&U.p0.sW2[k * 64 + j0 + i];
                acc0[i] += a * w4.x; acc0[i + 1] += a * w4.y; acc0[i + 2] += a * w4.z; acc0[i + 3] += a * w4.w;
            }
        }
#pragma unroll
        for (int i = 0; i < 16; i++) U.p0.sH2[n * 64 + j0 + i] = acc0[i];
        float ps = 0.f, pd = 0.f;
#pragma unroll
        for (int i = 0; i < 16; i++) { ps += acc0[i] * ws[O_G2AS + j0 + i]; pd += acc0[i] * ws[O_G2AD + j0 + i]; }
        red2[(n * 4 + jg) * 2] = ps;
        red2[(n * 4 + jg) * 2 + 1] = pd;
    }
    __syncthreads();
    if (tid < 64) {
        float s = 0.f, dd = 0.f;
        for (int g = 0; g < 4; g++) { s += red2[(tid * 4 + g) * 2]; dd += red2[(tid * 4 + g) * 2 + 1]; }
        sAs2[tid] = s; sAd2[tid] = dd;
    }
    __syncthreads();
    if (tid < 64) {
        float e = lrelu(sAs2[tid] + sAd2[sid]);
        float m = e;
        for (int o = 32; o; o >>= 1) m = fmaxf(m, __shfl_xor(m, o));
        float ex = __expf(e - m);
        float den = ex;
        for (int o = 32; o; o >>= 1) den += __shfl_xor(den, o);
        float inv = frcp(den + 1e-16f);
        float o_ = 0.f;
        for (int l = 0; l < 64; l++) {
            float a = __shfl(ex, l);
            o_ += a * U.p0.sH2[l * 64 + tid];
        }
        sSemb[tid] = o_ * inv + ws[O_G2B + tid];
    }
    if (tid < 64) sFB[tid] = ws[O_FB + tid];
    sLW[tid] = ws[O_LW + tid];
    if (tid < 4) sLB[tid] = ws[O_LB + tid];
    __syncthreads();

    {
        int c = tid >> 2, p = tid & 3;
        u16 px[16];
        const float* rp = seq + (size_t)(n0 + c) * 64 + p * 16;
#pragma unroll
        for (int i = 0; i < 16; i += 4) {
            float4 v = *(const float4*)&rp[i];
            px[i] = f2bf(v.x); px[i + 1] = f2bf(v.y); px[i + 2] = f2bf(v.z); px[i + 3] = f2bf(v.w);
        }
        *(uint4*)&U.p1.sV[c * 200 + p * 16] = *(const uint4*)&px[0];
        *(uint4*)&U.p1.sV[c * 200 + p * 16 + 8] = *(const uint4*)&px[8];
#pragma unroll
        for (int i = 0; i < 16; i++) px[i] = f2bf(sSemb[p * 16 + i]);
        *(uint4*)&U.p1.sV[c * 200 + 64 + p * 16] = *(const uint4*)&px[0];
        *(uint4*)&U.p1.sV[c * 200 + 64 + p * 16 + 8] = *(const uint4*)&px[8];
        const u16* ip = intra + (size_t)(n0 + c) * 64 + p * 16;
        *(uint4*)&U.p1.sV[c * 200 + 128 + p * 16] = *(const uint4*)ip;
        *(uint4*)&U.p1.sV[c * 200 + 128 + p * 16 + 8] = *(const uint4*)(ip + 8);
    }
    int lane = tid & 63, w = tid >> 6;
    int li = lane & 15, q = lane >> 4;
    int colw = w * 16 + li;
    const u16* fw16g = (const u16*)(ws + O_FW16);
    bfrag8 bwf[6];
#pragma unroll
    for (int kc = 0; kc < 6; kc++)
#pragma unroll
        for (int j = 0; j < 8; j++)
            bwf[kc][j] = (short)fw16g[(kc * 32 + q * 8 + j) * 64 + colw];
    __syncthreads();

    facc4 acc[4];
#pragma unroll
    for (int mt = 0; mt < 4; mt++) acc[mt] = (facc4){0.f, 0.f, 0.f, 0.f};
#pragma unroll
    for (int kc = 0; kc < 6; kc++) {
#pragma unroll
        for (int mt = 0; mt < 4; mt++) {
            bfrag8 av = *(const bfrag8*)&U.p1.sV[(mt * 16 + li) * 200 + kc * 32 + q * 8];
            acc[mt] = __builtin_amdgcn_mfma_f32_16x16x32_bf16(av, bwf[kc], acc[mt], 0, 0, 0);
        }
    }
    float fb = sFB[colw];
#pragma unroll
    for (int mt = 0; mt < 4; mt++)
#pragma unroll
        for (int r = 0; r < 4; r++) {
            float v = fmaxf(acc[mt][r] + fb, 0.f);
            U.p1.sFus[(mt * 16 + q * 4 + r) * 68 + colw] = v;
        }
    __syncthreads();

    if (tid < 64) {
        float l[4] = {sLB[0], sLB[1], sLB[2], sLB[3]};
        for (int j = 0; j < 64; j++) {
            float v = U.p1.sFus[tid * 68 + j];
            l[0] += v * sLW[j * 4 + 0];
            l[1] += v * sLW[j * 4 + 1];
            l[2] += v * sLW[j * 4 + 2];
            l[3] += v * sLW[j * 4 + 3];
        }
        float m = fmaxf(fmaxf(l[0], l[1]), fmaxf(l[2], l[3]));
        float e0 = __expf(l[0] - m), e1 = __expf(l[1] - m), e2 = __expf(l[2] - m), e3 = __expf(l[3] - m);
        float is = frcp(e0 + e1 + e2 + e3);
        float c0 = e0 * is;
        float c1 = c0 + e1 * is;
        float c2 = c1 + e2 * is;
        float c3 = c2 + e3 * is;
        const float lo = 5e-8f, hi = 1.0f - 5e-8f;
        c0 = fminf(fmaxf(c0, lo), hi);
        c1 = fminf(fmaxf(c1, lo), hi);
        c2 = fminf(fmaxf(c2, lo), hi);
        c3 = fminf(fmaxf(c3, lo), hi);
        size_t ob = (size_t)(n0 + tid) * 4;
        if (f32) {
            *(float4*)&((float*)out)[ob] = make_float4(c0, c1, c2, c3);
        } else {
            *(ushort4*)&((u16*)out)[ob] = make_ushort4(f2bf(c0), f2bf(c1), f2bf(c2), f2bf(c3));
        }
    }
}

extern "C" void kernel_launch(void* const* d_in, const int* in_sizes, int n_in,
                              void* d_out, int out_size, void* d_ws, size_t ws_size,
                              hipStream_t stream) {
    const void* daily = d_in[0];
    const int* inner = (const int*)d_in[1];
    const void* gamma = d_in[4];
    const void* beta = d_in[5];
    const void* wih = d_in[6];
    const void* whh = d_in[7];
    const void* bih = d_in[8];
    const void* bhh = d_in[9];
    const void* h0 = d_in[10];
    const void* g1w = d_in[11];
    const void* g1as = d_in[12];
    const void* g1ad = d_in[13];
    const void* g1b = d_in[14];
    const void* g2w = d_in[15];
    const void* g2as = d_in[16];
    const void* g2ad = d_in[17];
    const void* g2b = d_in[18];
    const void* fw = d_in[19];
    const void* fb = d_in[20];
    const void* lw = d_in[21];
    const void* lb = d_in[22];

    float* ws = (float*)d_ws;
    u16* h1g = (u16*)(ws + O_H1);
    u16* intra = (u16*)(ws + O_INTRA);
    u8* M8 = (u8*)(ws + O_M);

    hipMemsetAsync((void*)M8, 0, (size_t)NC * 256, stream);
    k_convert<<<64, 256, 0, stream>>>(gamma, wih, whh, bih, bhh, g1w, g1as, g1ad, g1b,
                                      g2w, g2as, g2ad, g2b, fw, fb, lw, lb, ws);
    k_bnpart<<<128, 256, 0, stream>>>(daily, gamma, ws + O_BNACC);
    k_edge<<<512, 256, 0, stream>>>(inner, (u32*)M8);
    k_gru<<<1024, 256, 0, stream>>>(daily, gamma, beta, h0, ws, ws + O_SEQ, h1g, ws + O_AS, ws + O_AD);
    k_gat1agg<<<256, 256, 0, stream>>>(h1g, ws, M8, ws + O_AS, ws + O_AD, intra, ws + O_SPOOL);
    k_fusion<<<256, 256, 0, stream>>>(ws + O_SEQ, ws + O_SPOOL, intra, ws, gamma, d_out);
}

// Round 10
// 218.710 us; speedup vs baseline: 1.0468x; 1.0468x over previous
//
#include <hip/hip_runtime.h>

#define NC 16384
#define WIN 32
#define DI 16
#define EI 524288

typedef unsigned short u16;
typedef unsigned char u8;
typedef unsigned int u32;
typedef __attribute__((ext_vector_type(8))) short bfrag8;
typedef __attribute__((ext_vector_type(4))) float facc4;

__device__ __forceinline__ float bf2f(u16 u) { return __uint_as_float(((u32)u) << 16); }
__device__ __forceinline__ u16 f2bf(float f) {
    u32 u = __float_as_uint(f);
    u += 0x7FFFu + ((u >> 16) & 1u);
    return (u16)(u >> 16);
}
__device__ __forceinline__ float frcp(float x) { return __builtin_amdgcn_rcpf(x); }
__device__ __forceinline__ float lrelu(float x) { return x >= 0.0f ? x : 0.2f * x; }
__device__ __forceinline__ float loadf(const void* p, size_t i, bool f32) {
    return f32 ? ((const float*)p)[i] : bf2f(((const u16*)p)[i]);
}
__device__ __forceinline__ bool is_f32(const void* gamma) {
    return ((const u32*)gamma)[0] == 0x3F800000u;
}

// ---- ws layout (float offsets) ----
#define O_SCALE 0
#define O_SHIFT 512
#define O_WIH   1024
#define O_WHH   4096
#define O_BIH   16384
#define O_BHH   16576
#define O_G1W   16768
#define O_G1AS  20864
#define O_G1AD  20928
#define O_G1B   20992
#define O_G2W   21056
#define O_G2AS  25152
#define O_G2AD  25216
#define O_G2B   25280
#define O_FB    25344
#define O_LW    25408
#define O_LB    25664
#define O_FW16  25668   /* 12288 u16 */
#define O_BNACC 31812   /* 1024 */
#define O_SEQ   40960   /* 16384*64 f32 */
#define O_H1    1089536 /* 16384*64 bf16 */
#define O_INTRA 1613824 /* 16384*64 bf16 */
#define O_SPOOL 2138112 /* 512*64 f32 partial maxes */
#define O_AS    2170880 /* 16384 f32 */
#define O_AD    2187264 /* 16384 f32 */
#define O_M     2203648 /* 16384*256 u8 */

// ---------------- K0: convert weights + zero bnacc + zero M8 ----------------
__global__ __launch_bounds__(256) void k_convert(const void* __restrict__ gamma,
                                                 const void* __restrict__ wih,
                                                 const void* __restrict__ whh,
                                                 const void* __restrict__ bih,
                                                 const void* __restrict__ bhh,
                                                 const void* __restrict__ g1w,
                                                 const void* __restrict__ g1as,
                                                 const void* __restrict__ g1ad,
                                                 const void* __restrict__ g1b,
                                                 const void* __restrict__ g2w,
                                                 const void* __restrict__ g2as,
                                                 const void* __restrict__ g2ad,
                                                 const void* __restrict__ g2b,
                                                 const void* __restrict__ fw,
                                                 const void* __restrict__ fb,
                                                 const void* __restrict__ lw,
                                                 const void* __restrict__ lb,
                                                 float* __restrict__ ws,
                                                 uint4* __restrict__ M16) {
    int gt = blockIdx.x * 256 + threadIdx.x;
    const int GS = 64 * 256;
    bool f32 = is_f32(gamma);
    u16* fw16 = (u16*)(ws + O_FW16);
    for (int i = gt; i < 3072; i += GS) ws[O_WIH + i] = loadf(wih, i, f32);
    for (int i = gt; i < 12288; i += GS) {
        ws[O_WHH + i] = loadf(whh, i, f32);
        fw16[i] = f32 ? f2bf(((const float*)fw)[i]) : ((const u16*)fw)[i];
    }
    for (int i = gt; i < 192; i += GS) {
        ws[O_BIH + i] = loadf(bih, i, f32);
        ws[O_BHH + i] = loadf(bhh, i, f32);
    }
    for (int i = gt; i < 4096; i += GS) {
        ws[O_G1W + i] = loadf(g1w, i, f32);
        ws[O_G2W + i] = loadf(g2w, i, f32);
    }
    if (gt < 64) {
        ws[O_G1AS + gt] = loadf(g1as, gt, f32);
        ws[O_G1AD + gt] = loadf(g1ad, gt, f32);
        ws[O_G1B + gt] = loadf(g1b, gt, f32);
        ws[O_G2AS + gt] = loadf(g2as, gt, f32);
        ws[O_G2AD + gt] = loadf(g2ad, gt, f32);
        ws[O_G2B + gt] = loadf(g2b, gt, f32);
        ws[O_FB + gt] = loadf(fb, gt, f32);
    }
    if (gt < 256) ws[O_LW + gt] = loadf(lw, gt, f32);
    if (gt < 4) ws[O_LB + gt] = loadf(lb, gt, f32);
    for (int i = gt; i < 1024; i += GS) ws[O_BNACC + i] = 0.f;
    const uint4 z4 = {0u, 0u, 0u, 0u};
    for (int i = gt; i < 262144; i += GS) M16[i] = z4;
}

// ---------------- K1: merged BN partial sums (blocks 0..127) + edge hist (128..639) ----------------
__global__ __launch_bounds__(256) void k_prep(const void* __restrict__ daily,
                                              const void* __restrict__ gamma,
                                              float* __restrict__ bnacc,
                                              const int* __restrict__ edges,
                                              u32* __restrict__ M32) {
    __shared__ float rS[256 * 17];
    __shared__ float rQ[256 * 17];
    int bid = blockIdx.x;
    int tid = threadIdx.x;
    if (bid >= 128) {
        int g = (bid - 128) * 256 + tid;
        int4 s4 = ((const int4*)edges)[g];
        int4 d4 = ((const int4*)(edges + EI))[g];
        int ss[4] = {s4.x, s4.y, s4.z, s4.w};
        int dd[4] = {d4.x, d4.y, d4.z, d4.w};
#pragma unroll
        for (int i = 0; i < 4; i++) {
            int sl = ss[i] & 255;
            atomicAdd(&M32[dd[i] * 64 + (sl >> 2)], 1u << ((sl & 3) * 8));
        }
        return;
    }
    int w = bid >> 2, ch = bid & 3;
    bool f32 = is_f32(gamma);
    float s[16], q[16];
#pragma unroll
    for (int i = 0; i < 16; i++) { s[i] = 0.f; q[i] = 0.f; }
    for (int it = 0; it < 16; it++) {
        int c = ch * 4096 + it * 256 + tid;
        size_t base = ((size_t)w * NC + c) * DI;
        float v[16];
        if (f32) {
            const float4* p = (const float4*)((const float*)daily + base);
            float4 a = p[0], b = p[1], cc = p[2], d = p[3];
            v[0] = a.x; v[1] = a.y; v[2] = a.z; v[3] = a.w;
            v[4] = b.x; v[5] = b.y; v[6] = b.z; v[7] = b.w;
            v[8] = cc.x; v[9] = cc.y; v[10] = cc.z; v[11] = cc.w;
            v[12] = d.x; v[13] = d.y; v[14] = d.z; v[15] = d.w;
        } else {
            const uint4* p = (const uint4*)((const u16*)daily + base);
            uint4 a = p[0], b = p[1];
            u32 us[8] = {a.x, a.y, a.z, a.w, b.x, b.y, b.z, b.w};
#pragma unroll
            for (int i = 0; i < 8; i++) {
                v[2 * i] = __uint_as_float(us[i] << 16);
                v[2 * i + 1] = __uint_as_float(us[i] & 0xFFFF0000u);
            }
        }
#pragma unroll
        for (int i = 0; i < 16; i++) { s[i] += v[i]; q[i] += v[i] * v[i]; }
    }
#pragma unroll
    for (int i = 0; i < 16; i++) { rS[tid * 17 + i] = s[i]; rQ[tid * 17 + i] = q[i]; }
    __syncthreads();
    int f = tid & 15, g = tid >> 4;
    float ss = 0.f, qq = 0.f;
    for (int t = g * 16; t < g * 16 + 16; t++) { ss += rS[t * 17 + f]; qq += rQ[t * 17 + f]; }
    atomicAdd(&bnacc[w * 16 + f], ss);
    atomicAdd(&bnacc[512 + w * 16 + f], qq);
}

// ---------------- K2: GRU — unchanged from round 9 (55 µs known-good) ----------------
__global__ __launch_bounds__(256, 4) void k_gru(const void* __restrict__ daily,
                                                const void* __restrict__ gamma,
                                                const void* __restrict__ beta,
                                                const void* __restrict__ h0_g,
                                                const float* __restrict__ ws,
                                                float* __restrict__ seq_out,
                                                u16* __restrict__ h1_out,
                                                float* __restrict__ asg,
                                                float* __restrict__ adg) {
    __shared__ __attribute__((aligned(16))) u16 sHd[2][16 * 72];
    __shared__ __attribute__((aligned(16))) u16 sXall[512 * 24];
    __shared__ float sSc[512], sSh[512];
    __shared__ float sRed[2][4][16];
    int tid = threadIdx.x;
    int w = tid >> 6, lane = tid & 63;
    int li = lane & 15, q = lane >> 4;
    int col = w * 16 + li;
    int n0 = blockIdx.x * 16;
    bool f32 = is_f32(gamma);

    for (int f = tid; f < 512; f += 256) {
        float mu = ws[O_BNACC + f] * (1.0f / NC);
        float var = ws[O_BNACC + 512 + f] * (1.0f / NC) - mu * mu;
        float sc = loadf(gamma, f, f32) * rsqrtf(var + 1e-5f);
        sSc[f] = sc;
        sSh[f] = loadf(beta, f, f32) - mu * sc;
    }
    __syncthreads();
    for (int R = tid; R < 512; R += 256) {
        int t = R >> 4, m = R & 15;
        size_t base = ((size_t)t * NC + n0 + m) * DI;
        float xv[16];
        if (f32) {
            const float4* p = (const float4*)((const float*)daily + base);
            float4 a = p[0], b = p[1], c = p[2], d = p[3];
            xv[0] = a.x; xv[1] = a.y; xv[2] = a.z; xv[3] = a.w;
            xv[4] = b.x; xv[5] = b.y; xv[6] = b.z; xv[7] = b.w;
            xv[8] = c.x; xv[9] = c.y; xv[10] = c.z; xv[11] = c.w;
            xv[12] = d.x; xv[13] = d.y; xv[14] = d.z; xv[15] = d.w;
        } else {
            const uint4* p = (const uint4*)((const u16*)daily + base);
            uint4 a = p[0], b = p[1];
            u32 us[8] = {a.x, a.y, a.z, a.w, b.x, b.y, b.z, b.w};
#pragma unroll
            for (int i = 0; i < 8; i++) {
                xv[2 * i] = __uint_as_float(us[i] << 16);
                xv[2 * i + 1] = __uint_as_float(us[i] & 0xFFFF0000u);
            }
        }
        u16 px[16];
#pragma unroll
        for (int i = 0; i < 16; i++) px[i] = f2bf(xv[i] * sSc[t * 16 + i] + sSh[t * 16 + i]);
        *(uint4*)&sXall[R * 24] = *(const uint4*)&px[0];
        *(uint4*)&sXall[R * 24 + 8] = *(const uint4*)&px[8];
    }

    bfrag8 bh[3][2], bx[3];
#pragma unroll
    for (int g = 0; g < 3; g++) {
        float sc = (g < 2) ? -1.0f : -2.0f;
#pragma unroll
        for (int kc = 0; kc < 2; kc++)
#pragma unroll
            for (int j = 0; j < 8; j++) {
                int k = kc * 32 + q * 8 + j;
                bh[g][kc][j] = (short)f2bf(sc * ws[O_WHH + k * 192 + g * 64 + col]);
            }
#pragma unroll
        for (int j = 0; j < 8; j++) {
            int k = q * 8 + j;
            bx[g][j] = (k < 16) ? (short)f2bf(sc * ws[O_WIH + k * 192 + g * 64 + col]) : (short)0;
        }
    }
    float bR = -1.0f * (ws[O_BIH + col] + ws[O_BHH + col]);
    float bZ = -1.0f * (ws[O_BIH + 64 + col] + ws[O_BHH + 64 + col]);
    float bNX = -2.0f * ws[O_BIH + 128 + col];
    float bNH = -2.0f * ws[O_BHH + 128 + col];

    float hC[4];
#pragma unroll
    for (int r = 0; r < 4; r++)
        hC[r] = loadf(h0_g, (size_t)(n0 + q * 4 + r) * 64 + col, f32);
    if (tid < 128) {
        int hr = tid >> 3, hc = (tid & 7) * 8;
        u16 hrow[8];
#pragma unroll
        for (int i = 0; i < 8; i++)
            hrow[i] = f2bf(loadf(h0_g, (size_t)(n0 + hr) * 64 + hc + i, f32));
        *(uint4*)&sHd[0][hr * 72 + hc] = *(const uint4*)&hrow[0];
    }
    __syncthreads();

    bool xl = (q < 2);
    for (int t = 0; t < WIN; t++) {
        int p = t & 1;
        bfrag8 ax = (bfrag8){0, 0, 0, 0, 0, 0, 0, 0};
        if (xl) ax = *(const bfrag8*)&sXall[(t * 16 + li) * 24 + q * 8];
        bfrag8 ah0 = *(const bfrag8*)&sHd[p][li * 72 + q * 8];
        bfrag8 ah1 = *(const bfrag8*)&sHd[p][li * 72 + 32 + q * 8];
        facc4 aR = __builtin_amdgcn_mfma_f32_16x16x32_bf16(ah0, bh[0][0], (facc4){bR, bR, bR, bR}, 0, 0, 0);
        facc4 aZ = __builtin_amdgcn_mfma_f32_16x16x32_bf16(ah0, bh[1][0], (facc4){bZ, bZ, bZ, bZ}, 0, 0, 0);
        facc4 aNH = __builtin_amdgcn_mfma_f32_16x16x32_bf16(ah0, bh[2][0], (facc4){bNH, bNH, bNH, bNH}, 0, 0, 0);
        facc4 aNX = __builtin_amdgcn_mfma_f32_16x16x32_bf16(ax, bx[2], (facc4){bNX, bNX, bNX, bNX}, 0, 0, 0);
        aR = __builtin_amdgcn_mfma_f32_16x16x32_bf16(ah1, bh[0][1], aR, 0, 0, 0);
        aZ = __builtin_amdgcn_mfma_f32_16x16x32_bf16(ah1, bh[1][1], aZ, 0, 0, 0);
        aNH = __builtin_amdgcn_mfma_f32_16x16x32_bf16(ah1, bh[2][1], aNH, 0, 0, 0);
        aR = __builtin_amdgcn_mfma_f32_16x16x32_bf16(ax, bx[0], aR, 0, 0, 0);
        aZ = __builtin_amdgcn_mfma_f32_16x16x32_bf16(ax, bx[1], aZ, 0, 0, 0);
#pragma unroll
        for (int r = 0; r < 4; r++) {
            float gr = frcp(1.0f + __expf(aR[r]));
            float gz = frcp(1.0f + __expf(aZ[r]));
            float narg = aNX[r] + gr * aNH[r];
            float gn = 2.0f * frcp(1.0f + __expf(narg)) - 1.0f;
            hC[r] = gn + gz * (hC[r] - gn);
        }
#pragma unroll
        for (int r = 0; r < 4; r++)
            sHd[p ^ 1][(q * 4 + r) * 72 + col] = f2bf(hC[r]);
        __syncthreads();
    }

#pragma unroll
    for (int r = 0; r < 4; r++)
        seq_out[(size_t)(n0 + q * 4 + r) * 64 + col] = hC[r];

    const facc4 zf = {0.f, 0.f, 0.f, 0.f};
    bfrag8 a0 = *(const bfrag8*)&sHd[0][li * 72 + q * 8];
    bfrag8 a1 = *(const bfrag8*)&sHd[0][li * 72 + 32 + q * 8];
    bfrag8 bg0, bg1;
#pragma unroll
    for (int j = 0; j < 8; j++) {
        bg0[j] = (short)f2bf(ws[O_G1W + (q * 8 + j) * 64 + col]);
        bg1[j] = (short)f2bf(ws[O_G1W + (32 + q * 8 + j) * 64 + col]);
    }
    facc4 acc = __builtin_amdgcn_mfma_f32_16x16x32_bf16(a0, bg0, zf, 0, 0, 0);
    acc = __builtin_amdgcn_mfma_f32_16x16x32_bf16(a1, bg1, acc, 0, 0, 0);
    float a1s_j = ws[O_G1AS + col], a1d_j = ws[O_G1AD + col];
    float pAs[4], pAd[4];
#pragma unroll
    for (int r = 0; r < 4; r++) {
        h1_out[(size_t)(n0 + q * 4 + r) * 64 + col] = f2bf(acc[r]);
        pAs[r] = acc[r] * a1s_j;
        pAd[r] = acc[r] * a1d_j;
    }
#pragma unroll
    for (int o = 1; o < 16; o <<= 1) {
#pragma unroll
        for (int r = 0; r < 4; r++) {
            pAs[r] += __shfl_xor(pAs[r], o);
            pAd[r] += __shfl_xor(pAd[r], o);
        }
    }
    if (li == 0) {
#pragma unroll
        for (int r = 0; r < 4; r++) {
            sRed[0][w][q * 4 + r] = pAs[r];
            sRed[1][w][q * 4 + r] = pAd[r];
        }
    }
    __syncthreads();
    if (tid < 16) {
        asg[n0 + tid] = sRed[0][0][tid] + sRed[0][1][tid] + sRed[0][2][tid] + sRed[0][3][tid];
        adg[n0 + tid] = sRed[1][0][tid] + sRed[1][1][tid] + sRed[1][2][tid] + sRed[1][3][tid];
    }
}

// ---------------- K3: GAT1 — 32 dsts/block (512 blocks, 2/CU), co-op P + MFMA ----------------
__global__ __launch_bounds__(256) void k_gat1agg(const u16* __restrict__ h1g,
                                                 const float* __restrict__ ws,
                                                 const u8* __restrict__ M8,
                                                 const float* __restrict__ asg,
                                                 const float* __restrict__ adg,
                                                 u16* __restrict__ intra,
                                                 float* __restrict__ spool8) {
    __shared__ __attribute__((aligned(16))) u16 hT[64 * 264];  // [feat][src] 33KB
    __shared__ __attribute__((aligned(16))) u16 sP[32 * 264];  // [dst_local][src] 16.5KB
    __shared__ float sAs[256], sAd[32], sB[64], sRS[32];
    __shared__ float sRSp[8][32];
    __shared__ float wmax[4];
    int tid = threadIdx.x;
    int sector = blockIdx.x >> 3;
    int dstbase = sector * 256 + (blockIdx.x & 7) * 32;
    int sbase = sector * 256;
    {
        const u16* row = h1g + (size_t)(sbase + tid) * 64;
#pragma unroll
        for (int c = 0; c < 16; c++) {
            uint2 v = ((const uint2*)row)[c];
            hT[(c * 4 + 0) * 264 + tid] = (u16)(v.x & 0xffff);
            hT[(c * 4 + 1) * 264 + tid] = (u16)(v.x >> 16);
            hT[(c * 4 + 2) * 264 + tid] = (u16)(v.y & 0xffff);
            hT[(c * 4 + 3) * 264 + tid] = (u16)(v.y >> 16);
        }
    }
    sAs[tid] = asg[sbase + tid];
    if (tid < 32) sAd[tid] = adg[dstbase + tid];
    if (tid < 64) sB[tid] = ws[O_G1B + tid];
    __syncthreads();
    int lane = tid & 63, w = tid >> 6;
    int li = lane & 15, q = lane >> 4;
    {
        float a = sAs[tid];
#pragma unroll
        for (int o = 1; o < 64; o <<= 1) a = fmaxf(a, __shfl_xor(a, o));
        if (lane == 0) wmax[w] = a;
    }
    __syncthreads();
    float maxA = fmaxf(fmaxf(wmax[0], wmax[1]), fmaxf(wmax[2], wmax[3]));

    // co-op P build: thread -> row tid>>3 (0..31), col-group tid&7 (32 cols)
    int prow = tid >> 3, pcg = tid & 7;
    {
        float adr_p = sAd[prow];
        float mrow_p = lrelu(maxA + adr_p);
        float lsum = 0.f;
        const u8* mp = M8 + (size_t)(dstbase + prow) * 256 + pcg * 32;
        uint4 mva = *(const uint4*)mp;
        uint4 mvb = *(const uint4*)(mp + 16);
        u32 wsrc[8] = {mva.x, mva.y, mva.z, mva.w, mvb.x, mvb.y, mvb.z, mvb.w};
#pragma unroll
        for (int i2 = 0; i2 < 16; i2++) {
            int i0 = 2 * i2;
            u32 mb0 = (wsrc[i0 >> 2] >> ((i0 & 3) * 8)) & 255u;
            u32 mb1 = (wsrc[i0 >> 2] >> (((i0 + 1) & 3) * 8)) & 255u;
            int c = pcg * 32 + i0;
            float e0 = lrelu(sAs[c] + adr_p);
            float e1 = lrelu(sAs[c + 1] + adr_p);
            float v0 = (float)mb0 * __expf(e0 - mrow_p);
            float v1 = (float)mb1 * __expf(e1 - mrow_p);
            u16 b0 = f2bf(v0), b1 = f2bf(v1);
            *(u32*)&sP[prow * 264 + pcg * 32 + i0] = (u32)b0 | ((u32)b1 << 16);
            lsum += bf2f(b0) + bf2f(b1);
        }
        sRSp[pcg][prow] = lsum;
    }
    __syncthreads();

    facc4 acc[2];
    acc[0] = (facc4){0.f, 0.f, 0.f, 0.f};
    acc[1] = (facc4){0.f, 0.f, 0.f, 0.f};
#pragma unroll
    for (int kc = 0; kc < 8; kc++) {
        bfrag8 bfh = *(const bfrag8*)&hT[(w * 16 + li) * 264 + kc * 32 + q * 8];
#pragma unroll
        for (int mt = 0; mt < 2; mt++) {
            bfrag8 af = *(const bfrag8*)&sP[(mt * 16 + li) * 264 + kc * 32 + q * 8];
            acc[mt] = __builtin_amdgcn_mfma_f32_16x16x32_bf16(af, bfh, acc[mt], 0, 0, 0);
        }
    }
    if (tid < 32) {
        float s = 0.f;
#pragma unroll
        for (int g = 0; g < 8; g++) s += sRSp[g][tid];
        sRS[tid] = s;
    }
    __syncthreads();

    float vmax = -1e30f;
    int colL = w * 16 + li;
#pragma unroll
    for (int mt = 0; mt < 2; mt++) {
#pragma unroll
        for (int r = 0; r < 4; r++) {
            int row = mt * 16 + q * 4 + r;
            int d = dstbase + row;
            int selfI = (blockIdx.x & 7) * 32 + row;
            float adr = sAd[row];
            float es = lrelu(sAs[selfI] + adr);
            float mrow = lrelu(maxA + adr);
            float exS = __expf(es - mrow);
            float denom = sRS[row] + exS;
            float inv = frcp(denom + 1e-16f);
            float selfh = bf2f(hT[colL * 264 + selfI]);
            float val = (acc[mt][r] + exS * selfh) * inv + sB[colL];
            intra[(size_t)d * 64 + colL] = f2bf(val);
            vmax = fmaxf(vmax, val);
        }
    }
    vmax = fmaxf(vmax, __shfl_xor(vmax, 16));
    vmax = fmaxf(vmax, __shfl_xor(vmax, 32));
    if (q == 0) spool8[(size_t)blockIdx.x * 64 + colL] = vmax;
}

// ---------------- K4: fusion (MFMA GAT2 prologue + MFMA fusion GEMM + logits) ----------------
__global__ __launch_bounds__(256) void k_fusion(const float* __restrict__ seq,
                                                const float* __restrict__ spool8,
                                                const u16* __restrict__ intra,
                                                const float* __restrict__ ws,
                                                const void* __restrict__ gamma,
                                                void* __restrict__ out) {
    __shared__ __attribute__((aligned(16))) union {
        struct { u16 sPmax[64 * 72]; float sH2[64 * 68]; } p0;
        struct { u16 sV[64 * 200]; float sFus[64 * 68]; } p1;
    } U;
    __shared__ float sSemb[64], sAs2[64], sAd2[64];
    __shared__ float sFB[64], sLW[256], sLB[4];
    __shared__ float red2[512];
    int tid = threadIdx.x, n0 = blockIdx.x * 64;
    int sid = blockIdx.x >> 2;
    bool f32 = is_f32(gamma);
    int lane = tid & 63, w = tid >> 6;
    int li = lane & 15, q = lane >> 4;
    int colw = w * 16 + li;

    // ---- phase 0: sector pool (8 partials) -> bf16 A-layout; GAT2 GEMM via MFMA ----
    for (int i = tid; i < 4096; i += 256) {
        int n = i >> 6, k = i & 63;
        const float* pp = &spool8[(size_t)(n * 8) * 64 + k];
        float m = pp[0];
#pragma unroll
        for (int p = 1; p < 8; p++) m = fmaxf(m, pp[p * 64]);
        U.p0.sPmax[n * 72 + k] = f2bf(m);
    }
    bfrag8 bw2[2];
#pragma unroll
    for (int kc = 0; kc < 2; kc++)
#pragma unroll
        for (int j = 0; j < 8; j++)
            bw2[kc][j] = (short)f2bf(ws[O_G2W + (kc * 32 + q * 8 + j) * 64 + colw]);
    __syncthreads();
    {
        const facc4 zf = {0.f, 0.f, 0.f, 0.f};
#pragma unroll
        for (int mt = 0; mt < 4; mt++) {
            bfrag8 af0 = *(const bfrag8*)&U.p0.sPmax[(mt * 16 + li) * 72 + q * 8];
            bfrag8 af1 = *(const bfrag8*)&U.p0.sPmax[(mt * 16 + li) * 72 + 32 + q * 8];
            facc4 a2 = __builtin_amdgcn_mfma_f32_16x16x32_bf16(af0, bw2[0], zf, 0, 0, 0);
            a2 = __builtin_amdgcn_mfma_f32_16x16x32_bf16(af1, bw2[1], a2, 0, 0, 0);
#pragma unroll
            for (int r = 0; r < 4; r++)
                U.p0.sH2[(mt * 16 + q * 4 + r) * 68 + colw] = a2[r];
        }
    }
    __syncthreads();
    {
        int n = tid >> 2, jg = tid & 3, j0 = jg * 16;
        float ps = 0.f, pd = 0.f;
#pragma unroll
        for (int i = 0; i < 16; i++) {
            float v = U.p0.sH2[n * 68 + j0 + i];
            ps += v * ws[O_G2AS + j0 + i];
            pd += v * ws[O_G2AD + j0 + i];
        }
        red2[(n * 4 + jg) * 2] = ps;
        red2[(n * 4 + jg) * 2 + 1] = pd;
    }
    __syncthreads();
    if (tid < 64) {
        float s = 0.f, dd = 0.f;
        for (int g = 0; g < 4; g++) { s += red2[(tid * 4 + g) * 2]; dd += red2[(tid * 4 + g) * 2 + 1]; }
        sAs2[tid] = s; sAd2[tid] = dd;
    }
    __syncthreads();
    if (tid < 64) {
        float e = lrelu(sAs2[tid] + sAd2[sid]);
        float m = e;
        for (int o = 32; o; o >>= 1) m = fmaxf(m, __shfl_xor(m, o));
        float ex = __expf(e - m);
        float den = ex;
        for (int o = 32; o; o >>= 1) den += __shfl_xor(den, o);
        float inv = frcp(den + 1e-16f);
        float o_ = 0.f;
        for (int l = 0; l < 64; l++) {
            float a = __shfl(ex, l);
            o_ += a * U.p0.sH2[l * 68 + tid];
        }
        sSemb[tid] = o_ * inv + ws[O_G2B + tid];
    }
    if (tid < 64) sFB[tid] = ws[O_FB + tid];
    sLW[tid] = ws[O_LW + tid];
    if (tid < 4) sLB[tid] = ws[O_LB + tid];
    __syncthreads();

    // ---- phase 1: stage V + fusion GEMM via MFMA ----
    {
        int c = tid >> 2, p = tid & 3;
        u16 px[16];
        const float* rp = seq + (size_t)(n0 + c) * 64 + p * 16;
#pragma unroll
        for (int i = 0; i < 16; i += 4) {
            float4 v = *(const float4*)&rp[i];
            px[i] = f2bf(v.x); px[i + 1] = f2bf(v.y); px[i + 2] = f2bf(v.z); px[i + 3] = f2bf(v.w);
        }
        *(uint4*)&U.p1.sV[c * 200 + p * 16] = *(const uint4*)&px[0];
        *(uint4*)&U.p1.sV[c * 200 + p * 16 + 8] = *(const uint4*)&px[8];
#pragma unroll
        for (int i = 0; i < 16; i++) px[i] = f2bf(sSemb[p * 16 + i]);
        *(uint4*)&U.p1.sV[c * 200 + 64 + p * 16] = *(const uint4*)&px[0];
        *(uint4*)&U.p1.sV[c * 200 + 64 + p * 16 + 8] = *(const uint4*)&px[8];
        const u16* ip = intra + (size_t)(n0 + c) * 64 + p * 16;
        *(uint4*)&U.p1.sV[c * 200 + 128 + p * 16] = *(const uint4*)ip;
        *(uint4*)&U.p1.sV[c * 200 + 128 + p * 16 + 8] = *(const uint4*)(ip + 8);
    }
    const u16* fw16g = (const u16*)(ws + O_FW16);
    bfrag8 bwf[6];
#pragma unroll
    for (int kc = 0; kc < 6; kc++)
#pragma unroll
        for (int j = 0; j < 8; j++)
            bwf[kc][j] = (short)fw16g[(kc * 32 + q * 8 + j) * 64 + colw];
    __syncthreads();

    facc4 acc[4];
#pragma unroll
    for (int mt = 0; mt < 4; mt++) acc[mt] = (facc4){0.f, 0.f, 0.f, 0.f};
#pragma unroll
    for (int kc = 0; kc < 6; kc++) {
#pragma unroll
        for (int mt = 0; mt < 4; mt++) {
            bfrag8 av = *(const bfrag8*)&U.p1.sV[(mt * 16 + li) * 200 + kc * 32 + q * 8];
            acc[mt] = __builtin_amdgcn_mfma_f32_16x16x32_bf16(av, bwf[kc], acc[mt], 0, 0, 0);
        }
    }
    float fb = sFB[colw];
#pragma unroll
    for (int mt = 0; mt < 4; mt++)
#pragma unroll
        for (int r = 0; r < 4; r++) {
            float v = fmaxf(acc[mt][r] + fb, 0.f);
            U.p1.sFus[(mt * 16 + q * 4 + r) * 68 + colw] = v;
        }
    __syncthreads();

    if (tid < 64) {
        float l[4] = {sLB[0], sLB[1], sLB[2], sLB[3]};
        for (int j = 0; j < 64; j++) {
            float v = U.p1.sFus[tid * 68 + j];
            l[0] += v * sLW[j * 4 + 0];
            l[1] += v * sLW[j * 4 + 1];
            l[2] += v * sLW[j * 4 + 2];
            l[3] += v * sLW[j * 4 + 3];
        }
        float m = fmaxf(fmaxf(l[0], l[1]), fmaxf(l[2], l[3]));
        float e0 = __expf(l[0] - m), e1 = __expf(l[1] - m), e2 = __expf(l[2] - m), e3 = __expf(l[3] - m);
        float is = frcp(e0 + e1 + e2 + e3);
        float c0 = e0 * is;
        float c1 = c0 + e1 * is;
        float c2 = c1 + e2 * is;
        float c3 = c2 + e3 * is;
        const float lo = 5e-8f, hi = 1.0f - 5e-8f;
        c0 = fminf(fmaxf(c0, lo), hi);
        c1 = fminf(fmaxf(c1, lo), hi);
        c2 = fminf(fmaxf(c2, lo), hi);
        c3 = fminf(fmaxf(c3, lo), hi);
        size_t ob = (size_t)(n0 + tid) * 4;
        if (f32) {
            *(float4*)&((float*)out)[ob] = make_float4(c0, c1, c2, c3);
        } else {
            *(ushort4*)&((u16*)out)[ob] = make_ushort4(f2bf(c0), f2bf(c1), f2bf(c2), f2bf(c3));
        }
    }
}

extern "C" void kernel_launch(void* const* d_in, const int* in_sizes, int n_in,
                              void* d_out, int out_size, void* d_ws, size_t ws_size,
                              hipStream_t stream) {
    const void* daily = d_in[0];
    const int* inner = (const int*)d_in[1];
    const void* gamma = d_in[4];
    const void* beta = d_in[5];
    const void* wih = d_in[6];
    const void* whh = d_in[7];
    const void* bih = d_in[8];
    const void* bhh = d_in[9];
    const void* h0 = d_in[10];
    const void* g1w = d_in[11];
    const void* g1as = d_in[12];
    const void* g1ad = d_in[13];
    const void* g1b = d_in[14];
    const void* g2w = d_in[15];
    const void* g2as = d_in[16];
    const void* g2ad = d_in[17];
    const void* g2b = d_in[18];
    const void* fw = d_in[19];
    const void* fb = d_in[20];
    const void* lw = d_in[21];
    const void* lb = d_in[22];

    float* ws = (float*)d_ws;
    u16* h1g = (u16*)(ws + O_H1);
    u16* intra = (u16*)(ws + O_INTRA);
    u8* M8 = (u8*)(ws + O_M);

    k_convert<<<64, 256, 0, stream>>>(gamma, wih, whh, bih, bhh, g1w, g1as, g1ad, g1b,
                                      g2w, g2as, g2ad, g2b, fw, fb, lw, lb, ws, (uint4*)M8);
    k_prep<<<640, 256, 0, stream>>>(daily, gamma, ws + O_BNACC, inner, (u32*)M8);
    k_gru<<<1024, 256, 0, stream>>>(daily, gamma, beta, h0, ws, ws + O_SEQ, h1g, ws + O_AS, ws + O_AD);
    k_gat1agg<<<512, 256, 0, stream>>>(h1g, ws, M8, ws + O_AS, ws + O_AD, intra, ws + O_SPOOL);
    k_fusion<<<256, 256, 0, stream>>>(ws + O_SEQ, ws + O_SPOOL, intra, ws, gamma, d_out);
}